// Round 7
// baseline (435.978 us; speedup 1.0000x reference)
//
#include <hip/hip_runtime.h>
#include <hip/hip_bf16.h>

#define N 8192
#define FIN 512
#define FOUT 64
#define ALPHA 0.2f

typedef __bf16 bf16x8 __attribute__((ext_vector_type(8)));
typedef __bf16 bf16x4 __attribute__((ext_vector_type(4)));
typedef float f32x4 __attribute__((ext_vector_type(4)));
typedef int i32x4 __attribute__((ext_vector_type(4)));

// ---- workspace layout (bytes) ----
// [0,64)               : Mkey (ordered-uint global max of f_dst)
// [32832, 65600)       : f_src (N floats)
// [65600, 98368)       : f_dst (N floats)
// [98368, 163904)      : WtG  (bf16 [FOUT][FIN], W transposed)
// [163904, 1212480)    : hT   (bf16 [FOUT][N], h transposed)
// [1212480, 17989696)  : num_part  (f32 [8][N][FOUT], per-y-slice partials)
// [17989696, 18251840) : lsum_part (f32 [8][N])

__device__ __forceinline__ unsigned enc_f(float x) {
    unsigned u = __float_as_uint(x);
    return (u & 0x80000000u) ? ~u : (u | 0x80000000u);
}
__device__ __forceinline__ float dec_f(unsigned u) {
    return (u & 0x80000000u) ? __uint_as_float(u & 0x7FFFFFFFu) : __uint_as_float(~u);
}

// async global->LDS, 16B per lane; LDS dest is wave-uniform base + lane*16
__device__ __forceinline__ void glds16(const void* g, void* l) {
    __builtin_amdgcn_global_load_lds((const __attribute__((address_space(1))) void*)g,
                                     (__attribute__((address_space(3))) void*)l, 16, 0, 0);
}
#define SFENCE() __builtin_amdgcn_sched_barrier(0)

// ---------- k_wt: WtG[f][k] = bf16(W[k][f]); also zero-init Mkey -----------
__global__ __launch_bounds__(64) void k_wt(const float* __restrict__ W,
                                           __bf16* __restrict__ WtG,
                                           unsigned* __restrict__ Mkey) {
    if (blockIdx.x == 0 && threadIdx.x == 0) *Mkey = 0u;  // < enc_f(any real)
    const int g = blockIdx.x * 64 + threadIdx.x;  // 0..4095
    const int k = g >> 3;
    const int f0 = (g & 7) * 8;
    const float4 w0 = *(const float4*)(W + (size_t)k * FOUT + f0);
    const float4 w1 = *(const float4*)(W + (size_t)k * FOUT + f0 + 4);
    WtG[(size_t)(f0 + 0) * FIN + k] = (__bf16)w0.x;
    WtG[(size_t)(f0 + 1) * FIN + k] = (__bf16)w0.y;
    WtG[(size_t)(f0 + 2) * FIN + k] = (__bf16)w0.z;
    WtG[(size_t)(f0 + 3) * FIN + k] = (__bf16)w0.w;
    WtG[(size_t)(f0 + 4) * FIN + k] = (__bf16)w1.x;
    WtG[(size_t)(f0 + 5) * FIN + k] = (__bf16)w1.y;
    WtG[(size_t)(f0 + 6) * FIN + k] = (__bf16)w1.z;
    WtG[(size_t)(f0 + 7) * FIN + k] = (__bf16)w1.w;
}

// ---------- k12: h=in@W (MFMA) -> f_src/f_dst/Mkey + hT (fused) ------------
__global__ __launch_bounds__(64) void k12(const float* __restrict__ in,
                                          const __bf16* __restrict__ WtG,
                                          const float* __restrict__ a,
                                          float* __restrict__ f_src,
                                          float* __restrict__ f_dst,
                                          unsigned* __restrict__ Mkey,
                                          __bf16* __restrict__ hT) {
    __shared__ __bf16 tb[64][16];
    const int lane = threadIdx.x;
    const int m = lane & 15, quad = lane >> 4;
    const int i0 = blockIdx.x * 16;

    f32x4 acc[4];
#pragma unroll
    for (int t = 0; t < 4; ++t) acc[t] = (f32x4){0.f, 0.f, 0.f, 0.f};

    const float* arow = in + (size_t)(i0 + m) * FIN + quad * 8;
    for (int k0 = 0; k0 < FIN; k0 += 32) {
        const float4 x0 = *(const float4*)(arow + k0);
        const float4 x1 = *(const float4*)(arow + k0 + 4);
        bf16x8 af;
        af[0] = (__bf16)x0.x; af[1] = (__bf16)x0.y; af[2] = (__bf16)x0.z; af[3] = (__bf16)x0.w;
        af[4] = (__bf16)x1.x; af[5] = (__bf16)x1.y; af[6] = (__bf16)x1.z; af[7] = (__bf16)x1.w;
#pragma unroll
        for (int t = 0; t < 4; ++t) {
            const bf16x8 bf = *(const bf16x8*)(WtG + (size_t)(t * 16 + m) * FIN + k0 + quad * 8);
            acc[t] = __builtin_amdgcn_mfma_f32_16x16x32_bf16(af, bf, acc[t], 0, 0, 0);
        }
    }
    float s1[4], s2[4];
#pragma unroll
    for (int r = 0; r < 4; ++r) { s1[r] = 0.f; s2[r] = 0.f; }
#pragma unroll
    for (int t = 0; t < 4; ++t) {
        const float a1 = a[t * 16 + m], a2 = a[64 + t * 16 + m];
#pragma unroll
        for (int r = 0; r < 4; ++r) {
            s1[r] += acc[t][r] * a1;
            s2[r] += acc[t][r] * a2;
        }
    }
#pragma unroll
    for (int off = 1; off <= 8; off <<= 1)
#pragma unroll
        for (int r = 0; r < 4; ++r) {
            s1[r] += __shfl_xor(s1[r], off);
            s2[r] += __shfl_xor(s2[r], off);
        }
    float lm = -1e30f;
    if (m == 0) {
#pragma unroll
        for (int r = 0; r < 4; ++r) {
            f_src[i0 + quad * 4 + r] = s1[r];
            f_dst[i0 + quad * 4 + r] = s2[r];
            lm = fmaxf(lm, s2[r]);
        }
    }
    lm = fmaxf(lm, __shfl_xor(lm, 16));
    lm = fmaxf(lm, __shfl_xor(lm, 32));
    if (lane == 0) atomicMax(Mkey, enc_f(lm));

#pragma unroll
    for (int t = 0; t < 4; ++t)
#pragma unroll
        for (int r = 0; r < 4; ++r) tb[t * 16 + m][quad * 4 + r] = (__bf16)acc[t][r];
    __syncthreads();
    {
        const int f = lane;
        const bf16x8 v0 = *(const bf16x8*)&tb[f][0];
        const bf16x8 v1 = *(const bf16x8*)&tb[f][8];
        *(bf16x8*)(hT + (size_t)f * N + i0) = v0;
        *(bf16x8*)(hT + (size_t)f * N + i0 + 8) = v1;
    }
}

// ---------- k3: fused mask+softmax-weight+PV, pipelined, JT=128 ------------
// Single-buffered sh (16 KB) + wl (16 KB) + sfd (4 KB) = 36 KB -> 4 blocks/CU.
// adj stream: 2-ahead register prefetch (adjv[2][8]); queue order [S][A] so
// vmcnt(8) publishes the stage while 8 adj loads stay in flight. 2 barriers/tile.
constexpr int JT = 128;
constexpr int NT = 1024 / JT;  // 8 tiles

__global__ __launch_bounds__(256, 4) void k3_attn(const int* __restrict__ adj,
                                                  const float* __restrict__ f_src,
                                                  const float* __restrict__ fdstG,
                                                  const unsigned* __restrict__ Mkey,
                                                  const __bf16* __restrict__ hT,
                                                  float* __restrict__ num_part,
                                                  float* __restrict__ lsum_part) {
    __shared__ __bf16 sh[64][JT];     // 16 KB, linear (glds dest)
    __shared__ __bf16 wl[4][16][JT];  // 16 KB, per-wave, XOR-swizzled
    __shared__ float sfd[1024];       //  4 KB
    const int tid = threadIdx.x;
    const int wv = tid >> 6, lane = tid & 63;
    const int m = lane & 15, quad = lane >> 4;
    const int rpar = lane >> 5;          // row parity (rows 2v+rpar)
    const int col4 = (lane & 31) * 4;    // 4-col chunk owned by this lane
    const int i0 = blockIdx.x * 64 + wv * 16;
    const int jb = blockIdx.y * 1024;
    const float LOG2E = 1.44269504088896f;

    // ---- prologue ----
    *(f32x4*)&sfd[tid * 4] = *(const f32x4*)(fdstG + jb + tid * 4);
    const float M = dec_f(*Mkey);
    // per-lane row terms (rows 2v+rpar only): 16 VGPR
    float fsv[8], shv[8];
#pragma unroll
    for (int v = 0; v < 8; ++v) {
        const float fs = f_src[i0 + 2 * v + rpar];
        const float t0 = fs + M;
        fsv[v] = fs;
        shv[v] = fmaxf(t0, ALPHA * t0) * LOG2E;
    }
    // glds source pointers (pre-swizzled column); wave covers rows wv*16..+16
    const __bf16* gsrc[4];
#pragma unroll
    for (int i = 0; i < 4; ++i) {
        const int f = (wv * 4 + i) * 4 + (lane >> 4);
        const int csw = ((lane & 15) * 8) ^ ((f & 7) << 3);
        gsrc[i] = hT + (size_t)f * N + jb + csw;
    }
    const int* apL = adj + (size_t)(i0 + rpar) * N + jb + col4;

    f32x4 acc[4];
#pragma unroll
    for (int t = 0; t < 4; ++t) acc[t] = (f32x4){0.f, 0.f, 0.f, 0.f};
    f32x4 accl = (f32x4){0.f, 0.f, 0.f, 0.f};
    bf16x8 bones;
#pragma unroll
    for (int jj = 0; jj < 8; ++jj) bones[jj] = (__bf16)(m == 0 ? 1.0f : 0.0f);

    // ---- pipeline prologue: stage(0) + adj(0) + adj(1) ----
    i32x4 adjv[2][8];
#pragma unroll
    for (int i = 0; i < 4; ++i) glds16(gsrc[i], &sh[(wv * 4 + i) * 4][0]);
    SFENCE();
#pragma unroll
    for (int v = 0; v < 8; ++v)
        adjv[0][v] = __builtin_nontemporal_load((const i32x4*)(apL + (size_t)(2 * v) * N));
    SFENCE();
#pragma unroll
    for (int v = 0; v < 8; ++v)
        adjv[1][v] = __builtin_nontemporal_load((const i32x4*)(apL + (size_t)(2 * v) * N + JT));
    SFENCE();
    // queue: [S0 x4][A0 x8][A1 x8]; drain S0 (and sfd ds_writes), keep A0/A1 flying
    asm volatile("s_waitcnt lgkmcnt(0)" ::: "memory");
    asm volatile("s_waitcnt vmcnt(16)" ::: "memory");
    SFENCE();
    __builtin_amdgcn_s_barrier();
    SFENCE();

#pragma unroll
    for (int t = 0; t < NT; ++t) {
        const int jt = t * JT;
        const int cur = t & 1;
        // ---- C: exp-weights from adjv[cur] -> wl (wave-private; compiler
        //      auto-inserts the vmcnt wait for adjv[cur])
        const f32x4 fd = *(const f32x4*)&sfd[jt + col4];
#pragma unroll
        for (int v = 0; v < 8; ++v) {
            bf16x4 wb;
#pragma unroll
            for (int c = 0; c < 4; ++c) {
                float e = fsv[v] + fd[c];
                e = fmaxf(e, ALPHA * e);
                const float ex = __builtin_amdgcn_exp2f(e * LOG2E - shv[v]);
                wb[c] = (__bf16)(adjv[cur][v][c] > 0 ? ex : 0.f);
            }
            const int rr = 2 * v + rpar;
            *(bf16x4*)&wl[wv][rr][col4 ^ ((rr & 7) << 3)] = wb;
        }
        SFENCE();
        // ---- D: MFMA; A from wl, B from sh (swizzled col index)
#pragma unroll
        for (int jj0 = 0; jj0 < JT; jj0 += 64) {
#pragma unroll
            for (int u = 0; u < 2; ++u) {
                const int cb = jj0 + u * 32 + quad * 8;
                const int cs = cb ^ ((m & 7) << 3);
                const bf16x8 af = *(const bf16x8*)&wl[wv][m][cs];
#pragma unroll
                for (int tt = 0; tt < 4; ++tt) {
                    const bf16x8 bfr = *(const bf16x8*)&sh[tt * 16 + m][cs];
                    acc[tt] = __builtin_amdgcn_mfma_f32_16x16x32_bf16(af, bfr, acc[tt], 0, 0, 0);
                }
                accl = __builtin_amdgcn_mfma_f32_16x16x32_bf16(af, bones, accl, 0, 0, 0);
            }
        }
        SFENCE();
        if (t < NT - 1) {
            // ---- barrier: all waves done reading sh(t); safe to overwrite
            asm volatile("s_waitcnt lgkmcnt(0)" ::: "memory");
            SFENCE();
            __builtin_amdgcn_s_barrier();
            SFENCE();
            // ---- issue stage(t+1) into sh
#pragma unroll
            for (int i = 0; i < 4; ++i)
                glds16(gsrc[i] + jt + JT, &sh[(wv * 4 + i) * 4][0]);
            SFENCE();
            // ---- issue adj(t+2) into adjv[cur] (freed by C above)
            if (t < NT - 2) {
#pragma unroll
                for (int v = 0; v < 8; ++v)
                    adjv[cur][v] = __builtin_nontemporal_load(
                        (const i32x4*)(apL + (size_t)(2 * v) * N + jt + 2 * JT));
                SFENCE();
                // queue: [A(t+1) 8][S(t+1) 4][A(t+2) 8] -> drain thru S(t+1)
                asm volatile("s_waitcnt vmcnt(8)" ::: "memory");
            } else {
                asm volatile("s_waitcnt vmcnt(0)" ::: "memory");
            }
            SFENCE();
            // ---- publish sh(t+1)
            __builtin_amdgcn_s_barrier();
            SFENCE();
        }
    }
    // epilogue: plain stores to this y-slice's partial buffers
    float* npb = num_part + (size_t)blockIdx.y * N * FOUT;
#pragma unroll
    for (int t = 0; t < 4; ++t)
#pragma unroll
        for (int r = 0; r < 4; ++r)
            npb[(size_t)(i0 + quad * 4 + r) * FOUT + t * 16 + m] = acc[t][r];
    if (m == 0) {
#pragma unroll
        for (int r = 0; r < 4; ++r)
            lsum_part[(size_t)blockIdx.y * N + i0 + quad * 4 + r] = accl[r];
    }
}

// ---------- k4: out = leaky(sum_p num_part / sum_p lsum_part, 0.01) --------
__global__ __launch_bounds__(256) void k4_norm(float* __restrict__ out,
                                               const float* __restrict__ num_part,
                                               const float* __restrict__ lsum_part) {
    const int idx = blockIdx.x * 256 + threadIdx.x;
    const int i = idx >> 6;
    float s = 0.f, l = 0.f;
#pragma unroll
    for (int p = 0; p < 8; ++p) {
        s += num_part[(size_t)p * N * FOUT + idx];
        l += lsum_part[(size_t)p * N + i];
    }
    const float v = s / (l > 0.f ? l : 1.f);
    out[idx] = v > 0.f ? v : 0.01f * v;
}

extern "C" void kernel_launch(void* const* d_in, const int* in_sizes, int n_in,
                              void* d_out, int out_size, void* d_ws, size_t ws_size,
                              hipStream_t stream) {
    const float* in = (const float*)d_in[0];
    const int* adj = (const int*)d_in[1];
    const float* W = (const float*)d_in[2];
    const float* a = (const float*)d_in[3];
    float* out = (float*)d_out;

    char* ws = (char*)d_ws;
    unsigned* Mkey = (unsigned*)ws;
    float* f_src = (float*)(ws + 32832);
    float* f_dst = (float*)(ws + 65600);
    __bf16* WtG = (__bf16*)(ws + 98368);
    __bf16* hT = (__bf16*)(ws + 163904);
    float* num_part = (float*)(ws + 1212480);
    float* lsum_part = (float*)(ws + 17989696);

    k_wt<<<64, 64, 0, stream>>>(W, WtG, Mkey);  // also zero-inits Mkey
    k12<<<N / 16, 64, 0, stream>>>(in, WtG, a, f_src, f_dst, Mkey, hT);

    dim3 g3(N / 64, 8);
    k3_attn<<<g3, 256, 0, stream>>>(adj, f_src, f_dst, Mkey, hT, num_part, lsum_part);
    k4_norm<<<(N * FOUT) / 256, 256, 0, stream>>>(out, num_part, lsum_part);
}

// Round 8
// 400.305 us; speedup vs baseline: 1.0891x; 1.0891x over previous
//
#include <hip/hip_runtime.h>
#include <hip/hip_bf16.h>

#define N 8192
#define FIN 512
#define FOUT 64
#define ALPHA 0.2f

typedef __bf16 bf16x8 __attribute__((ext_vector_type(8)));
typedef __bf16 bf16x4 __attribute__((ext_vector_type(4)));
typedef float f32x4 __attribute__((ext_vector_type(4)));
typedef int i32x4 __attribute__((ext_vector_type(4)));

// ---- workspace layout (bytes) ----
// [0,64)               : Mkey (ordered-uint global max of f_dst)
// [32832, 65600)       : f_src (N floats)
// [65600, 98368)       : f_dst (N floats)
// [98368, 163904)      : WtG  (bf16 [FOUT][FIN], W transposed)
// [163904, 1212480)    : hT   (bf16 [FOUT][N], h transposed)
// [1212480, 17989696)  : num_part  (f32 [8][N][FOUT], per-y-slice partials)
// [17989696, 18251840) : lsum_part (f32 [8][N])

__device__ __forceinline__ unsigned enc_f(float x) {
    unsigned u = __float_as_uint(x);
    return (u & 0x80000000u) ? ~u : (u | 0x80000000u);
}
__device__ __forceinline__ float dec_f(unsigned u) {
    return (u & 0x80000000u) ? __uint_as_float(u & 0x7FFFFFFFu) : __uint_as_float(~u);
}

// async global->LDS, 16B per lane; LDS dest is wave-uniform base + lane*16
__device__ __forceinline__ void glds16(const void* g, void* l) {
    __builtin_amdgcn_global_load_lds((const __attribute__((address_space(1))) void*)g,
                                     (__attribute__((address_space(3))) void*)l, 16, 0, 0);
}
#define SFENCE() __builtin_amdgcn_sched_barrier(0)

// ---------- k_wt: WtG[f][k] = bf16(W[k][f]); also zero-init Mkey -----------
__global__ __launch_bounds__(64) void k_wt(const float* __restrict__ W,
                                           __bf16* __restrict__ WtG,
                                           unsigned* __restrict__ Mkey) {
    if (blockIdx.x == 0 && threadIdx.x == 0) *Mkey = 0u;  // < enc_f(any real)
    const int g = blockIdx.x * 64 + threadIdx.x;  // 0..4095
    const int k = g >> 3;
    const int f0 = (g & 7) * 8;
    const float4 w0 = *(const float4*)(W + (size_t)k * FOUT + f0);
    const float4 w1 = *(const float4*)(W + (size_t)k * FOUT + f0 + 4);
    WtG[(size_t)(f0 + 0) * FIN + k] = (__bf16)w0.x;
    WtG[(size_t)(f0 + 1) * FIN + k] = (__bf16)w0.y;
    WtG[(size_t)(f0 + 2) * FIN + k] = (__bf16)w0.z;
    WtG[(size_t)(f0 + 3) * FIN + k] = (__bf16)w0.w;
    WtG[(size_t)(f0 + 4) * FIN + k] = (__bf16)w1.x;
    WtG[(size_t)(f0 + 5) * FIN + k] = (__bf16)w1.y;
    WtG[(size_t)(f0 + 6) * FIN + k] = (__bf16)w1.z;
    WtG[(size_t)(f0 + 7) * FIN + k] = (__bf16)w1.w;
}

// ---------- k12: h=in@W (MFMA) -> f_src/f_dst/Mkey + hT (fused) ------------
__global__ __launch_bounds__(64) void k12(const float* __restrict__ in,
                                          const __bf16* __restrict__ WtG,
                                          const float* __restrict__ a,
                                          float* __restrict__ f_src,
                                          float* __restrict__ f_dst,
                                          unsigned* __restrict__ Mkey,
                                          __bf16* __restrict__ hT) {
    __shared__ __bf16 tb[64][16];
    const int lane = threadIdx.x;
    const int m = lane & 15, quad = lane >> 4;
    const int i0 = blockIdx.x * 16;

    f32x4 acc[4];
#pragma unroll
    for (int t = 0; t < 4; ++t) acc[t] = (f32x4){0.f, 0.f, 0.f, 0.f};

    const float* arow = in + (size_t)(i0 + m) * FIN + quad * 8;
    for (int k0 = 0; k0 < FIN; k0 += 32) {
        const float4 x0 = *(const float4*)(arow + k0);
        const float4 x1 = *(const float4*)(arow + k0 + 4);
        bf16x8 af;
        af[0] = (__bf16)x0.x; af[1] = (__bf16)x0.y; af[2] = (__bf16)x0.z; af[3] = (__bf16)x0.w;
        af[4] = (__bf16)x1.x; af[5] = (__bf16)x1.y; af[6] = (__bf16)x1.z; af[7] = (__bf16)x1.w;
#pragma unroll
        for (int t = 0; t < 4; ++t) {
            const bf16x8 bf = *(const bf16x8*)(WtG + (size_t)(t * 16 + m) * FIN + k0 + quad * 8);
            acc[t] = __builtin_amdgcn_mfma_f32_16x16x32_bf16(af, bf, acc[t], 0, 0, 0);
        }
    }
    float s1[4], s2[4];
#pragma unroll
    for (int r = 0; r < 4; ++r) { s1[r] = 0.f; s2[r] = 0.f; }
#pragma unroll
    for (int t = 0; t < 4; ++t) {
        const float a1 = a[t * 16 + m], a2 = a[64 + t * 16 + m];
#pragma unroll
        for (int r = 0; r < 4; ++r) {
            s1[r] += acc[t][r] * a1;
            s2[r] += acc[t][r] * a2;
        }
    }
#pragma unroll
    for (int off = 1; off <= 8; off <<= 1)
#pragma unroll
        for (int r = 0; r < 4; ++r) {
            s1[r] += __shfl_xor(s1[r], off);
            s2[r] += __shfl_xor(s2[r], off);
        }
    float lm = -1e30f;
    if (m == 0) {
#pragma unroll
        for (int r = 0; r < 4; ++r) {
            f_src[i0 + quad * 4 + r] = s1[r];
            f_dst[i0 + quad * 4 + r] = s2[r];
            lm = fmaxf(lm, s2[r]);
        }
    }
    lm = fmaxf(lm, __shfl_xor(lm, 16));
    lm = fmaxf(lm, __shfl_xor(lm, 32));
    if (lane == 0) atomicMax(Mkey, enc_f(lm));

#pragma unroll
    for (int t = 0; t < 4; ++t)
#pragma unroll
        for (int r = 0; r < 4; ++r) tb[t * 16 + m][quad * 4 + r] = (__bf16)acc[t][r];
    __syncthreads();
    {
        const int f = lane;
        const bf16x8 v0 = *(const bf16x8*)&tb[f][0];
        const bf16x8 v1 = *(const bf16x8*)&tb[f][8];
        *(bf16x8*)(hT + (size_t)f * N + i0) = v0;
        *(bf16x8*)(hT + (size_t)f * N + i0 + 8) = v1;
    }
}

// ---------- k3: fused mask+softmax-weight+PV, 8-wave pipelined, JT=128 -----
// R5 pipeline (dbuf sh, [S][A] queue, vmcnt(8) barriers) at 512-thread blocks:
// grid (64,8)=512 == 2 blocks/CU x 256 CU -> exact packing, zero tail.
// adjv single-buffered (A(t+1) issued right after C(t) frees it) -> ~110 VGPR
// so 2 blocks/CU stand at launch_bounds(512,4). One 16KB stage serves 128 rows.
constexpr int JT = 128;
constexpr int NT = 1024 / JT;  // 8 tiles

__global__ __launch_bounds__(512, 4) void k3_attn(const int* __restrict__ adj,
                                                  const float* __restrict__ f_src,
                                                  const float* __restrict__ fdstG,
                                                  const unsigned* __restrict__ Mkey,
                                                  const __bf16* __restrict__ hT,
                                                  float* __restrict__ num_part,
                                                  float* __restrict__ lsum_part) {
    __shared__ __bf16 sh[2][64][JT];  // 32 KB, linear (glds dest), double-buffered
    __shared__ __bf16 wl[8][16][JT];  // 32 KB, per-wave, XOR-swizzled
    __shared__ float sfd[1024];       //  4 KB
    const int tid = threadIdx.x;
    const int wv = tid >> 6, lane = tid & 63;
    const int m = lane & 15, quad = lane >> 4;
    const int rpar = lane >> 5;          // row parity (rows 2v+rpar)
    const int col4 = (lane & 31) * 4;    // 4-col chunk owned by this lane
    const int i0 = blockIdx.x * 128 + wv * 16;
    const int jb = blockIdx.y * 1024;
    const float LOG2E = 1.44269504088896f;

    // ---- prologue ----
    if (tid < 256) *(f32x4*)&sfd[tid * 4] = *(const f32x4*)(fdstG + jb + tid * 4);
    const float M = dec_f(*Mkey);
    float fsv[8], shv[8];  // per-lane row terms (rows 2v+rpar): 16 VGPR
#pragma unroll
    for (int v = 0; v < 8; ++v) {
        const float fs = f_src[i0 + 2 * v + rpar];
        const float t0 = fs + M;
        fsv[v] = fs;
        shv[v] = fmaxf(t0, ALPHA * t0) * LOG2E;
    }
    // glds source pointers (pre-swizzled column); wave wv stages f-rows wv*8..+8
    const __bf16* gsrc[2];
#pragma unroll
    for (int i = 0; i < 2; ++i) {
        const int f = wv * 8 + i * 4 + (lane >> 4);
        const int csw = ((lane & 15) * 8) ^ ((f & 7) << 3);
        gsrc[i] = hT + (size_t)f * N + jb + csw;
    }
    const int* apL = adj + (size_t)(i0 + rpar) * N + jb + col4;

    SFENCE();
    __syncthreads();  // sfd visible; vm queue fully drained here
    SFENCE();

    f32x4 acc[4];
#pragma unroll
    for (int t = 0; t < 4; ++t) acc[t] = (f32x4){0.f, 0.f, 0.f, 0.f};
    f32x4 accl = (f32x4){0.f, 0.f, 0.f, 0.f};
    bf16x8 bones;
#pragma unroll
    for (int jj = 0; jj < 8; ++jj) bones[jj] = (__bf16)(m == 0 ? 1.0f : 0.0f);

    // ---- pipeline prologue: stage(0) + adj(0); queue = [S0 x2][A0 x8] ----
    i32x4 adjv[8];
#pragma unroll
    for (int i = 0; i < 2; ++i) glds16(gsrc[i], &sh[0][wv * 8 + i * 4][0]);
    SFENCE();
#pragma unroll
    for (int v = 0; v < 8; ++v)
        adjv[v] = __builtin_nontemporal_load((const i32x4*)(apL + (size_t)(2 * v) * N));
    SFENCE();

#pragma unroll
    for (int t = 0; t < NT; ++t) {
        const int jt = t * JT;
        const int cur = t & 1, nxt = cur ^ 1;
        // ---- barrier A: S(t) done (vmcnt(8) leaves the 8 adj loads flying)
        asm volatile("s_waitcnt vmcnt(8)" ::: "memory");
        SFENCE();
        __builtin_amdgcn_s_barrier();
        SFENCE();
        // ---- issue S(t+1) into sh[nxt] (readers of sh[nxt] fenced by barrier B(t-1))
        if (t < NT - 1) {
#pragma unroll
            for (int i = 0; i < 2; ++i)
                glds16(gsrc[i] + jt + JT, &sh[nxt][wv * 8 + i * 4][0]);
        }
        SFENCE();
        // ---- C: exp-weights from adjv (compiler inserts vmcnt(2): drains A(t),
        //      leaves S(t+1) in flight) -> wl, XOR-swizzled
        const f32x4 fd = *(const f32x4*)&sfd[jt + col4];
#pragma unroll
        for (int v = 0; v < 8; ++v) {
            bf16x4 wb;
#pragma unroll
            for (int c = 0; c < 4; ++c) {
                float e = fsv[v] + fd[c];
                e = fmaxf(e, ALPHA * e);
                const float ex = __builtin_amdgcn_exp2f(e * LOG2E - shv[v]);
                wb[c] = (__bf16)(adjv[v][c] > 0 ? ex : 0.f);
            }
            const int rr = 2 * v + rpar;
            *(bf16x4*)&wl[wv][rr][col4 ^ ((rr & 7) << 3)] = wb;
        }
        SFENCE();
        // ---- issue A(t+1) into adjv (registers freed by C above); these fly
        //      across D(t) + barrier B + S-issue: ~HBM latency covered
        if (t < NT - 1) {
#pragma unroll
            for (int v = 0; v < 8; ++v)
                adjv[v] = __builtin_nontemporal_load(
                    (const i32x4*)(apL + (size_t)(2 * v) * N + jt + JT));
        }
        SFENCE();
        // ---- D: MFMA; A from wl, B from sh[cur] (same swizzled col index)
#pragma unroll
        for (int jj0 = 0; jj0 < JT; jj0 += 64) {
#pragma unroll
            for (int u = 0; u < 2; ++u) {
                const int cb = jj0 + u * 32 + quad * 8;
                const int cs = cb ^ ((m & 7) << 3);
                const bf16x8 af = *(const bf16x8*)&wl[wv][m][cs];
#pragma unroll
                for (int tt = 0; tt < 4; ++tt) {
                    const bf16x8 bfr = *(const bf16x8*)&sh[cur][tt * 16 + m][cs];
                    acc[tt] = __builtin_amdgcn_mfma_f32_16x16x32_bf16(af, bfr, acc[tt], 0, 0, 0);
                }
                accl = __builtin_amdgcn_mfma_f32_16x16x32_bf16(af, bones, accl, 0, 0, 0);
            }
        }
        SFENCE();
        // ---- barrier B: all waves' ds_reads of sh[cur] complete
        if (t < NT - 1) {
            asm volatile("s_waitcnt lgkmcnt(0)" ::: "memory");
            SFENCE();
            __builtin_amdgcn_s_barrier();
            SFENCE();
        }
    }
    // epilogue: plain stores to this y-slice's partial buffers
    float* npb = num_part + (size_t)blockIdx.y * N * FOUT;
#pragma unroll
    for (int t = 0; t < 4; ++t)
#pragma unroll
        for (int r = 0; r < 4; ++r)
            npb[(size_t)(i0 + quad * 4 + r) * FOUT + t * 16 + m] = acc[t][r];
    if (m == 0) {
#pragma unroll
        for (int r = 0; r < 4; ++r)
            lsum_part[(size_t)blockIdx.y * N + i0 + quad * 4 + r] = accl[r];
    }
}

// ---------- k4: out = leaky(sum_p num_part / sum_p lsum_part, 0.01) --------
__global__ __launch_bounds__(256) void k4_norm(float* __restrict__ out,
                                               const float* __restrict__ num_part,
                                               const float* __restrict__ lsum_part) {
    const int idx = blockIdx.x * 256 + threadIdx.x;
    const int i = idx >> 6;
    float s = 0.f, l = 0.f;
#pragma unroll
    for (int p = 0; p < 8; ++p) {
        s += num_part[(size_t)p * N * FOUT + idx];
        l += lsum_part[(size_t)p * N + i];
    }
    const float v = s / (l > 0.f ? l : 1.f);
    out[idx] = v > 0.f ? v : 0.01f * v;
}

extern "C" void kernel_launch(void* const* d_in, const int* in_sizes, int n_in,
                              void* d_out, int out_size, void* d_ws, size_t ws_size,
                              hipStream_t stream) {
    const float* in = (const float*)d_in[0];
    const int* adj = (const int*)d_in[1];
    const float* W = (const float*)d_in[2];
    const float* a = (const float*)d_in[3];
    float* out = (float*)d_out;

    char* ws = (char*)d_ws;
    unsigned* Mkey = (unsigned*)ws;
    float* f_src = (float*)(ws + 32832);
    float* f_dst = (float*)(ws + 65600);
    __bf16* WtG = (__bf16*)(ws + 98368);
    __bf16* hT = (__bf16*)(ws + 163904);
    float* num_part = (float*)(ws + 1212480);
    float* lsum_part = (float*)(ws + 17989696);

    k_wt<<<64, 64, 0, stream>>>(W, WtG, Mkey);  // also zero-inits Mkey
    k12<<<N / 16, 64, 0, stream>>>(in, WtG, a, f_src, f_dst, Mkey, hT);

    dim3 g3(N / 128, 8);
    k3_attn<<<g3, 512, 0, stream>>>(adj, f_src, f_dst, Mkey, hT, num_part, lsum_part);
    k4_norm<<<(N * FOUT) / 256, 256, 0, stream>>>(out, num_part, lsum_part);
}

// Round 9
// 387.188 us; speedup vs baseline: 1.1260x; 1.0339x over previous
//
#include <hip/hip_runtime.h>
#include <hip/hip_bf16.h>

#define N 8192
#define FIN 512
#define FOUT 64
#define ALPHA 0.2f

typedef __bf16 bf16x8 __attribute__((ext_vector_type(8)));
typedef __bf16 bf16x4 __attribute__((ext_vector_type(4)));
typedef float f32x4 __attribute__((ext_vector_type(4)));
typedef int i32x4 __attribute__((ext_vector_type(4)));

// ---- workspace layout (bytes) ----
// [0,64)               : Mkey (ordered-uint global max of f_dst)
// [32832, 65600)       : f_src (N floats)
// [65600, 98368)       : f_dst (N floats)
// [98368, 163904)      : WtG  (bf16 [FOUT][FIN], W transposed)
// [163904, 1212480)    : hT   (bf16 [FOUT][N], h transposed)
// [1212480, 17989696)  : num_part  (f32 [8][N][FOUT], per-y-slice partials)
// [17989696, 18251840) : lsum_part (f32 [8][N])

__device__ __forceinline__ unsigned enc_f(float x) {
    unsigned u = __float_as_uint(x);
    return (u & 0x80000000u) ? ~u : (u | 0x80000000u);
}
__device__ __forceinline__ float dec_f(unsigned u) {
    return (u & 0x80000000u) ? __uint_as_float(u & 0x7FFFFFFFu) : __uint_as_float(~u);
}

// async global->LDS, 16B per lane; LDS dest is wave-uniform base + lane*16
__device__ __forceinline__ void glds16(const void* g, void* l) {
    __builtin_amdgcn_global_load_lds((const __attribute__((address_space(1))) void*)g,
                                     (__attribute__((address_space(3))) void*)l, 16, 0, 0);
}
#define SFENCE() __builtin_amdgcn_sched_barrier(0)

// ---------- k_wt: WtG[f][k] = bf16(W[k][f]); also zero-init Mkey -----------
__global__ __launch_bounds__(64) void k_wt(const float* __restrict__ W,
                                           __bf16* __restrict__ WtG,
                                           unsigned* __restrict__ Mkey) {
    if (blockIdx.x == 0 && threadIdx.x == 0) *Mkey = 0u;  // < enc_f(any real)
    const int g = blockIdx.x * 64 + threadIdx.x;  // 0..4095
    const int k = g >> 3;
    const int f0 = (g & 7) * 8;
    const float4 w0 = *(const float4*)(W + (size_t)k * FOUT + f0);
    const float4 w1 = *(const float4*)(W + (size_t)k * FOUT + f0 + 4);
    WtG[(size_t)(f0 + 0) * FIN + k] = (__bf16)w0.x;
    WtG[(size_t)(f0 + 1) * FIN + k] = (__bf16)w0.y;
    WtG[(size_t)(f0 + 2) * FIN + k] = (__bf16)w0.z;
    WtG[(size_t)(f0 + 3) * FIN + k] = (__bf16)w0.w;
    WtG[(size_t)(f0 + 4) * FIN + k] = (__bf16)w1.x;
    WtG[(size_t)(f0 + 5) * FIN + k] = (__bf16)w1.y;
    WtG[(size_t)(f0 + 6) * FIN + k] = (__bf16)w1.z;
    WtG[(size_t)(f0 + 7) * FIN + k] = (__bf16)w1.w;
}

// ---------- k12: h=in@W, 4-way K-split (4 waves/block, 8 waves/CU) ---------
// Wave w computes partial over K in [128w, 128w+128); LDS tree-reduce; wave 0
// finishes f_src/f_dst/Mkey, wave 1 stores hT.
__global__ __launch_bounds__(256) void k12(const float* __restrict__ in,
                                           const __bf16* __restrict__ WtG,
                                           const float* __restrict__ a,
                                           float* __restrict__ f_src,
                                           float* __restrict__ f_dst,
                                           unsigned* __restrict__ Mkey,
                                           __bf16* __restrict__ hT) {
    __shared__ float red[4][4][4][64];  // [src_wave][t][r][lane] : 16 KB
    __shared__ float sred[4][4][4][2];  // [src_wave][quad][r][{s1,s2}] : 512 B
    __shared__ __bf16 tb[64][16];       // 2 KB transpose buffer
    const int tid = threadIdx.x;
    const int wv = tid >> 6, lane = tid & 63;
    const int m = lane & 15, quad = lane >> 4;
    const int i0 = blockIdx.x * 16;

    f32x4 acc[4];
#pragma unroll
    for (int t = 0; t < 4; ++t) acc[t] = (f32x4){0.f, 0.f, 0.f, 0.f};

    const float* arow = in + (size_t)(i0 + m) * FIN + wv * 128 + quad * 8;
    const __bf16* wrow = WtG + wv * 128 + quad * 8;
#pragma unroll
    for (int k0 = 0; k0 < 128; k0 += 32) {
        const float4 x0 = *(const float4*)(arow + k0);
        const float4 x1 = *(const float4*)(arow + k0 + 4);
        bf16x8 af;
        af[0] = (__bf16)x0.x; af[1] = (__bf16)x0.y; af[2] = (__bf16)x0.z; af[3] = (__bf16)x0.w;
        af[4] = (__bf16)x1.x; af[5] = (__bf16)x1.y; af[6] = (__bf16)x1.z; af[7] = (__bf16)x1.w;
#pragma unroll
        for (int t = 0; t < 4; ++t) {
            const bf16x8 bf = *(const bf16x8*)(wrow + (size_t)(t * 16 + m) * FIN + k0);
            acc[t] = __builtin_amdgcn_mfma_f32_16x16x32_bf16(af, bf, acc[t], 0, 0, 0);
        }
    }
    // cross-wave K-reduce via LDS
#pragma unroll
    for (int t = 0; t < 4; ++t)
#pragma unroll
        for (int r = 0; r < 4; ++r) red[wv][t][r][lane] = acc[t][r];
    __syncthreads();
    // wave wv owns fout block t=wv after the reduce
    float facc[4];
#pragma unroll
    for (int r = 0; r < 4; ++r)
        facc[r] = red[0][wv][r][lane] + red[1][wv][r][lane] +
                  red[2][wv][r][lane] + red[3][wv][r][lane];
    // partial f_src/f_dst over this wave's 16 fouts
    const float a1 = a[wv * 16 + m], a2 = a[64 + wv * 16 + m];
    float p1[4], p2[4];
#pragma unroll
    for (int r = 0; r < 4; ++r) { p1[r] = facc[r] * a1; p2[r] = facc[r] * a2; }
#pragma unroll
    for (int off = 1; off <= 8; off <<= 1)
#pragma unroll
        for (int r = 0; r < 4; ++r) {
            p1[r] += __shfl_xor(p1[r], off);
            p2[r] += __shfl_xor(p2[r], off);
        }
    if (m == 0)
#pragma unroll
        for (int r = 0; r < 4; ++r) {
            sred[wv][quad][r][0] = p1[r];
            sred[wv][quad][r][1] = p2[r];
        }
    // transpose buffer for hT (fout = wv*16+m, row = quad*4+r)
#pragma unroll
    for (int r = 0; r < 4; ++r) tb[wv * 16 + m][quad * 4 + r] = (__bf16)facc[r];
    __syncthreads();
    if (wv == 0) {
        float lm = -1e30f;
        if (lane < 16) {
            const int q = lane >> 2, r = lane & 3;
            const float s1 = sred[0][q][r][0] + sred[1][q][r][0] +
                             sred[2][q][r][0] + sred[3][q][r][0];
            const float s2 = sred[0][q][r][1] + sred[1][q][r][1] +
                             sred[2][q][r][1] + sred[3][q][r][1];
            f_src[i0 + lane] = s1;
            f_dst[i0 + lane] = s2;
            lm = s2;
        }
#pragma unroll
        for (int off = 1; off <= 32; off <<= 1) lm = fmaxf(lm, __shfl_xor(lm, off));
        if (lane == 0) atomicMax(Mkey, enc_f(lm));
    } else if (wv == 1) {
        const int f = lane;
        const bf16x8 v0 = *(const bf16x8*)&tb[f][0];
        const bf16x8 v1 = *(const bf16x8*)&tb[f][8];
        *(bf16x8*)(hT + (size_t)f * N + i0) = v0;
        *(bf16x8*)(hT + (size_t)f * N + i0 + 8) = v1;
    }
}

// ---------- k3: fused mask+softmax-weight+PV, pipelined, JT=128 ------------
// R5 configuration (verbatim): dbuf sh via global_load_lds, dbuf adjv,
// counted vmcnt(8) leaves adj loads in flight across barriers. 3 blocks/CU.
constexpr int JT = 128;

__global__ __launch_bounds__(256, 3) void k3_attn(const int* __restrict__ adj,
                                                  const float* __restrict__ f_src,
                                                  const float* __restrict__ fdstG,
                                                  const unsigned* __restrict__ Mkey,
                                                  const __bf16* __restrict__ hT,
                                                  float* __restrict__ num_part,
                                                  float* __restrict__ lsum_part) {
    __shared__ __bf16 sh[2][64][JT];   // 32 KB, linear (glds dest)
    __shared__ __bf16 wl[4][16][JT];   // 16 KB, per-wave, XOR-swizzled
    __shared__ float sfd[1024];        //  4 KB
    const int tid = threadIdx.x;
    const int wv = tid >> 6, lane = tid & 63;
    const int m = lane & 15, quad = lane >> 4;
    const int rpar = lane >> 5;
    const int col4 = (lane & 31) * 4;
    const int i0 = blockIdx.x * 64 + wv * 16;
    const int jb = blockIdx.y * 1024;
    const float LOG2E = 1.44269504088896f;

    // ---- prologue: sfd + wave-uniform row terms; then full drain ----
    *(f32x4*)&sfd[tid * 4] = *(const f32x4*)(fdstG + jb + tid * 4);
    const float M = dec_f(*Mkey);
    float fsr[16], shl[16];
#pragma unroll
    for (int r = 0; r < 16; ++r) {
        const float fs =
            __uint_as_float(__builtin_amdgcn_readfirstlane(__float_as_uint(f_src[i0 + r])));
        const float t0 = fs + M;
        fsr[r] = fs;
        shl[r] = fmaxf(t0, ALPHA * t0) * LOG2E;
    }
    // per-lane glds source pointers (pre-swizzled column)
    const __bf16* gsrc[4];
#pragma unroll
    for (int i = 0; i < 4; ++i) {
        const int f = (wv * 4 + i) * 4 + (lane >> 4);
        const int csw = ((lane & 15) * 8) ^ ((f & 7) << 3);
        gsrc[i] = hT + (size_t)f * N + jb + csw;
    }
    const int* apL = adj + (size_t)(i0 + rpar) * N + jb + col4;

    SFENCE();
    __syncthreads();  // sfd visible; vm queue fully drained (vmcnt==0 here)
    SFENCE();

    f32x4 acc[4];
#pragma unroll
    for (int t = 0; t < 4; ++t) acc[t] = (f32x4){0.f, 0.f, 0.f, 0.f};
    f32x4 accl = (f32x4){0.f, 0.f, 0.f, 0.f};
    bf16x8 bones;
#pragma unroll
    for (int jj = 0; jj < 8; ++jj) bones[jj] = (__bf16)(m == 0 ? 1.0f : 0.0f);

    // ---- pipeline prologue: stage(0) + adj(0) ----
    i32x4 adjv[2][8];
#pragma unroll
    for (int i = 0; i < 4; ++i) glds16(gsrc[i], &sh[0][(wv * 4 + i) * 4][0]);
    SFENCE();
#pragma unroll
    for (int v = 0; v < 8; ++v)
        adjv[0][v] = __builtin_nontemporal_load((const i32x4*)(apL + (size_t)(2 * v) * N));
    SFENCE();
    // queue now: stage(0)[4 oldest] + adj(0)[8]

#pragma unroll
    for (int t = 0; t < 8; ++t) {
        const int jt = t * JT;
        const int cur = t & 1, nxt = cur ^ 1;
        // ---- barrier A: own stage(t) done (adj(t) stays in flight), rendezvous
        asm volatile("s_waitcnt vmcnt(8)" ::: "memory");
        SFENCE();
        __builtin_amdgcn_s_barrier();
        SFENCE();
        // ---- issue stage(t+1) into sh[nxt] (reads of sh[nxt] ended at barrier B(t-1))
        if (t < 7) {
#pragma unroll
            for (int i = 0; i < 4; ++i)
                glds16(gsrc[i] + jt + JT, &sh[nxt][(wv * 4 + i) * 4][0]);
        }
        SFENCE();
        // ---- issue adj(t+1)
        if (t < 7) {
#pragma unroll
            for (int v = 0; v < 8; ++v)
                adjv[nxt][v] = __builtin_nontemporal_load(
                    (const i32x4*)(apL + (size_t)(2 * v) * N + jt + JT));
        }
        SFENCE();
        // ---- C: exp-weights from adjv[cur] -> wl (wave-private, no barrier)
        const f32x4 fd0 = *(const f32x4*)&sfd[jt + col4];
#pragma unroll
        for (int v = 0; v < 8; ++v) {
            const float fs_l = rpar ? fsr[2 * v + 1] : fsr[2 * v];
            const float sh_l = rpar ? shl[2 * v + 1] : shl[2 * v];
            bf16x4 wb;
#pragma unroll
            for (int c = 0; c < 4; ++c) {
                float e = fs_l + fd0[c];
                e = fmaxf(e, ALPHA * e);
                const float ex = __builtin_amdgcn_exp2f(e * LOG2E - sh_l);
                wb[c] = (__bf16)(adjv[cur][v][c] > 0 ? ex : 0.f);
            }
            const int rr = 2 * v + rpar;
            *(bf16x4*)&wl[wv][rr][col4 ^ ((rr & 7) << 3)] = wb;
        }
        SFENCE();
        // ---- D: MFMA; A from wl, B from sh[cur] (swizzled read)
#pragma unroll
        for (int jj0 = 0; jj0 < JT; jj0 += 64) {
#pragma unroll
            for (int u = 0; u < 2; ++u) {
                const int cb = jj0 + u * 32 + quad * 8;
                const int cs = cb ^ ((m & 7) << 3);
                const bf16x8 af = *(const bf16x8*)&wl[wv][m][cs];
#pragma unroll
                for (int tt = 0; tt < 4; ++tt) {
                    const bf16x8 bfr = *(const bf16x8*)&sh[cur][tt * 16 + m][cs];
                    acc[tt] = __builtin_amdgcn_mfma_f32_16x16x32_bf16(af, bfr, acc[tt], 0, 0, 0);
                }
                accl = __builtin_amdgcn_mfma_f32_16x16x32_bf16(af, bones, accl, 0, 0, 0);
            }
        }
        SFENCE();
        // ---- barrier B: all waves done reading sh[cur]
        if (t < 7) {
            asm volatile("s_waitcnt lgkmcnt(0)" ::: "memory");
            SFENCE();
            __builtin_amdgcn_s_barrier();
            SFENCE();
        }
    }
    // epilogue: plain stores to this y-slice's partial buffers
    float* npb = num_part + (size_t)blockIdx.y * N * FOUT;
#pragma unroll
    for (int t = 0; t < 4; ++t)
#pragma unroll
        for (int r = 0; r < 4; ++r)
            npb[(size_t)(i0 + quad * 4 + r) * FOUT + t * 16 + m] = acc[t][r];
    if (m == 0) {
#pragma unroll
        for (int r = 0; r < 4; ++r)
            lsum_part[(size_t)blockIdx.y * N + i0 + quad * 4 + r] = accl[r];
    }
}

// ---------- k4: out = leaky(sum_p num_part / sum_p lsum_part, 0.01) --------
__global__ __launch_bounds__(256) void k4_norm(float* __restrict__ out,
                                               const float* __restrict__ num_part,
                                               const float* __restrict__ lsum_part) {
    const int idx = blockIdx.x * 256 + threadIdx.x;
    const int i = idx >> 6;
    float s = 0.f, l = 0.f;
#pragma unroll
    for (int p = 0; p < 8; ++p) {
        s += num_part[(size_t)p * N * FOUT + idx];
        l += lsum_part[(size_t)p * N + i];
    }
    const float v = s / (l > 0.f ? l : 1.f);
    out[idx] = v > 0.f ? v : 0.01f * v;
}

extern "C" void kernel_launch(void* const* d_in, const int* in_sizes, int n_in,
                              void* d_out, int out_size, void* d_ws, size_t ws_size,
                              hipStream_t stream) {
    const float* in = (const float*)d_in[0];
    const int* adj = (const int*)d_in[1];
    const float* W = (const float*)d_in[2];
    const float* a = (const float*)d_in[3];
    float* out = (float*)d_out;

    char* ws = (char*)d_ws;
    unsigned* Mkey = (unsigned*)ws;
    float* f_src = (float*)(ws + 32832);
    float* f_dst = (float*)(ws + 65600);
    __bf16* WtG = (__bf16*)(ws + 98368);
    __bf16* hT = (__bf16*)(ws + 163904);
    float* num_part = (float*)(ws + 1212480);
    float* lsum_part = (float*)(ws + 17989696);

    k_wt<<<64, 64, 0, stream>>>(W, WtG, Mkey);  // also zero-inits Mkey
    k12<<<N / 16, 256, 0, stream>>>(in, WtG, a, f_src, f_dst, Mkey, hT);

    dim3 g3(N / 64, 8);
    k3_attn<<<g3, 256, 0, stream>>>(adj, f_src, f_dst, Mkey, hT, num_part, lsum_part);
    k4_norm<<<(N * FOUT) / 256, 256, 0, stream>>>(out, num_part, lsum_part);
}

// Round 10
// 382.018 us; speedup vs baseline: 1.1413x; 1.0135x over previous
//
#include <hip/hip_runtime.h>
#include <hip/hip_bf16.h>

#define N 8192
#define FIN 512
#define FOUT 64
#define ALPHA 0.2f

typedef __bf16 bf16x8 __attribute__((ext_vector_type(8)));
typedef __bf16 bf16x4 __attribute__((ext_vector_type(4)));
typedef float f32x4 __attribute__((ext_vector_type(4)));
typedef int i32x4 __attribute__((ext_vector_type(4)));

// ---- workspace layout (bytes) ----
// [0,64)               : Mkey (ordered-uint global max of f_dst)
// [32832, 65600)       : f_src (N floats)
// [65600, 98368)       : f_dst (N floats)
// [98368, 163904)      : WtG  (bf16 [FOUT][FIN], W transposed)
// [163904, 1212480)    : hT   (bf16 [FOUT][N], h transposed)
// [1212480, 17989696)  : num_part  (f32 [4][N][FOUT], per-y-slice partials)
// [17989696, 18251840) : lsum_part (f32 [4][N])

__device__ __forceinline__ unsigned enc_f(float x) {
    unsigned u = __float_as_uint(x);
    return (u & 0x80000000u) ? ~u : (u | 0x80000000u);
}
__device__ __forceinline__ float dec_f(unsigned u) {
    return (u & 0x80000000u) ? __uint_as_float(u & 0x7FFFFFFFu) : __uint_as_float(~u);
}

// async global->LDS, 16B per lane; LDS dest is wave-uniform base + lane*16
__device__ __forceinline__ void glds16(const void* g, void* l) {
    __builtin_amdgcn_global_load_lds((const __attribute__((address_space(1))) void*)g,
                                     (__attribute__((address_space(3))) void*)l, 16, 0, 0);
}
#define SFENCE() __builtin_amdgcn_sched_barrier(0)

// ---------- k_wt: WtG[f][k] = bf16(W[k][f]); also zero-init Mkey -----------
__global__ __launch_bounds__(64) void k_wt(const float* __restrict__ W,
                                           __bf16* __restrict__ WtG,
                                           unsigned* __restrict__ Mkey) {
    if (blockIdx.x == 0 && threadIdx.x == 0) *Mkey = 0u;  // < enc_f(any real)
    const int g = blockIdx.x * 64 + threadIdx.x;  // 0..4095
    const int k = g >> 3;
    const int f0 = (g & 7) * 8;
    const float4 w0 = *(const float4*)(W + (size_t)k * FOUT + f0);
    const float4 w1 = *(const float4*)(W + (size_t)k * FOUT + f0 + 4);
    WtG[(size_t)(f0 + 0) * FIN + k] = (__bf16)w0.x;
    WtG[(size_t)(f0 + 1) * FIN + k] = (__bf16)w0.y;
    WtG[(size_t)(f0 + 2) * FIN + k] = (__bf16)w0.z;
    WtG[(size_t)(f0 + 3) * FIN + k] = (__bf16)w0.w;
    WtG[(size_t)(f0 + 4) * FIN + k] = (__bf16)w1.x;
    WtG[(size_t)(f0 + 5) * FIN + k] = (__bf16)w1.y;
    WtG[(size_t)(f0 + 6) * FIN + k] = (__bf16)w1.z;
    WtG[(size_t)(f0 + 7) * FIN + k] = (__bf16)w1.w;
}

// ---------- k12: h=in@W, 4-way K-split (4 waves/block, 8 waves/CU) ---------
__global__ __launch_bounds__(256) void k12(const float* __restrict__ in,
                                           const __bf16* __restrict__ WtG,
                                           const float* __restrict__ a,
                                           float* __restrict__ f_src,
                                           float* __restrict__ f_dst,
                                           unsigned* __restrict__ Mkey,
                                           __bf16* __restrict__ hT) {
    __shared__ float red[4][4][4][64];  // [src_wave][t][r][lane] : 16 KB
    __shared__ float sred[4][4][4][2];  // [src_wave][quad][r][{s1,s2}] : 512 B
    __shared__ __bf16 tb[64][16];       // 2 KB transpose buffer
    const int tid = threadIdx.x;
    const int wv = tid >> 6, lane = tid & 63;
    const int m = lane & 15, quad = lane >> 4;
    const int i0 = blockIdx.x * 16;

    f32x4 acc[4];
#pragma unroll
    for (int t = 0; t < 4; ++t) acc[t] = (f32x4){0.f, 0.f, 0.f, 0.f};

    const float* arow = in + (size_t)(i0 + m) * FIN + wv * 128 + quad * 8;
    const __bf16* wrow = WtG + wv * 128 + quad * 8;
#pragma unroll
    for (int k0 = 0; k0 < 128; k0 += 32) {
        const float4 x0 = *(const float4*)(arow + k0);
        const float4 x1 = *(const float4*)(arow + k0 + 4);
        bf16x8 af;
        af[0] = (__bf16)x0.x; af[1] = (__bf16)x0.y; af[2] = (__bf16)x0.z; af[3] = (__bf16)x0.w;
        af[4] = (__bf16)x1.x; af[5] = (__bf16)x1.y; af[6] = (__bf16)x1.z; af[7] = (__bf16)x1.w;
#pragma unroll
        for (int t = 0; t < 4; ++t) {
            const bf16x8 bf = *(const bf16x8*)(wrow + (size_t)(t * 16 + m) * FIN + k0);
            acc[t] = __builtin_amdgcn_mfma_f32_16x16x32_bf16(af, bf, acc[t], 0, 0, 0);
        }
    }
    // cross-wave K-reduce via LDS
#pragma unroll
    for (int t = 0; t < 4; ++t)
#pragma unroll
        for (int r = 0; r < 4; ++r) red[wv][t][r][lane] = acc[t][r];
    __syncthreads();
    float facc[4];
#pragma unroll
    for (int r = 0; r < 4; ++r)
        facc[r] = red[0][wv][r][lane] + red[1][wv][r][lane] +
                  red[2][wv][r][lane] + red[3][wv][r][lane];
    const float a1 = a[wv * 16 + m], a2 = a[64 + wv * 16 + m];
    float p1[4], p2[4];
#pragma unroll
    for (int r = 0; r < 4; ++r) { p1[r] = facc[r] * a1; p2[r] = facc[r] * a2; }
#pragma unroll
    for (int off = 1; off <= 8; off <<= 1)
#pragma unroll
        for (int r = 0; r < 4; ++r) {
            p1[r] += __shfl_xor(p1[r], off);
            p2[r] += __shfl_xor(p2[r], off);
        }
    if (m == 0)
#pragma unroll
        for (int r = 0; r < 4; ++r) {
            sred[wv][quad][r][0] = p1[r];
            sred[wv][quad][r][1] = p2[r];
        }
#pragma unroll
    for (int r = 0; r < 4; ++r) tb[wv * 16 + m][quad * 4 + r] = (__bf16)facc[r];
    __syncthreads();
    if (wv == 0) {
        float lm = -1e30f;
        if (lane < 16) {
            const int q = lane >> 2, r = lane & 3;
            const float s1 = sred[0][q][r][0] + sred[1][q][r][0] +
                             sred[2][q][r][0] + sred[3][q][r][0];
            const float s2 = sred[0][q][r][1] + sred[1][q][r][1] +
                             sred[2][q][r][1] + sred[3][q][r][1];
            f_src[i0 + lane] = s1;
            f_dst[i0 + lane] = s2;
            lm = s2;
        }
#pragma unroll
        for (int off = 1; off <= 32; off <<= 1) lm = fmaxf(lm, __shfl_xor(lm, off));
        if (lane == 0) atomicMax(Mkey, enc_f(lm));
    } else if (wv == 1) {
        const int f = lane;
        const bf16x8 v0 = *(const bf16x8*)&tb[f][0];
        const bf16x8 v1 = *(const bf16x8*)&tb[f][8];
        *(bf16x8*)(hT + (size_t)f * N + i0) = v0;
        *(bf16x8*)(hT + (size_t)f * N + i0 + 8) = v1;
    }
}

// ---------- k3: fused mask+softmax-weight+PV, pipelined, JT=128 ------------
// R5/R9 pipeline verbatim; y-split 8->4 (j-range 2048/block). LDS 56 KB ->
// 2 blocks/CU; grid (128,4)=512 == 2x256 -> perfect packing, zero tail.
constexpr int JT = 128;
constexpr int JR = 2048;       // j-range per block
constexpr int NT = JR / JT;    // 16 tiles

__global__ __launch_bounds__(256, 2) void k3_attn(const int* __restrict__ adj,
                                                  const float* __restrict__ f_src,
                                                  const float* __restrict__ fdstG,
                                                  const unsigned* __restrict__ Mkey,
                                                  const __bf16* __restrict__ hT,
                                                  float* __restrict__ num_part,
                                                  float* __restrict__ lsum_part) {
    __shared__ __bf16 sh[2][64][JT];   // 32 KB, linear (glds dest)
    __shared__ __bf16 wl[4][16][JT];   // 16 KB, per-wave, XOR-swizzled
    __shared__ float sfd[JR];          //  8 KB
    const int tid = threadIdx.x;
    const int wv = tid >> 6, lane = tid & 63;
    const int m = lane & 15, quad = lane >> 4;
    const int rpar = lane >> 5;
    const int col4 = (lane & 31) * 4;
    const int i0 = blockIdx.x * 64 + wv * 16;
    const int jb = blockIdx.y * JR;
    const float LOG2E = 1.44269504088896f;

    // ---- prologue: sfd (2048 floats) + wave-uniform row terms; full drain ----
    *(f32x4*)&sfd[tid * 4] = *(const f32x4*)(fdstG + jb + tid * 4);
    *(f32x4*)&sfd[1024 + tid * 4] = *(const f32x4*)(fdstG + jb + 1024 + tid * 4);
    const float M = dec_f(*Mkey);
    float fsr[16], shl[16];
#pragma unroll
    for (int r = 0; r < 16; ++r) {
        const float fs =
            __uint_as_float(__builtin_amdgcn_readfirstlane(__float_as_uint(f_src[i0 + r])));
        const float t0 = fs + M;
        fsr[r] = fs;
        shl[r] = fmaxf(t0, ALPHA * t0) * LOG2E;
    }
    // per-lane glds source pointers (pre-swizzled column)
    const __bf16* gsrc[4];
#pragma unroll
    for (int i = 0; i < 4; ++i) {
        const int f = (wv * 4 + i) * 4 + (lane >> 4);
        const int csw = ((lane & 15) * 8) ^ ((f & 7) << 3);
        gsrc[i] = hT + (size_t)f * N + jb + csw;
    }
    const int* apL = adj + (size_t)(i0 + rpar) * N + jb + col4;

    SFENCE();
    __syncthreads();  // sfd visible; vm queue fully drained (vmcnt==0 here)
    SFENCE();

    f32x4 acc[4];
#pragma unroll
    for (int t = 0; t < 4; ++t) acc[t] = (f32x4){0.f, 0.f, 0.f, 0.f};
    f32x4 accl = (f32x4){0.f, 0.f, 0.f, 0.f};
    bf16x8 bones;
#pragma unroll
    for (int jj = 0; jj < 8; ++jj) bones[jj] = (__bf16)(m == 0 ? 1.0f : 0.0f);

    // ---- pipeline prologue: stage(0) + adj(0) ----
    i32x4 adjv[2][8];
#pragma unroll
    for (int i = 0; i < 4; ++i) glds16(gsrc[i], &sh[0][(wv * 4 + i) * 4][0]);
    SFENCE();
#pragma unroll
    for (int v = 0; v < 8; ++v)
        adjv[0][v] = __builtin_nontemporal_load((const i32x4*)(apL + (size_t)(2 * v) * N));
    SFENCE();
    // queue now: stage(0)[4 oldest] + adj(0)[8]

#pragma unroll
    for (int t = 0; t < NT; ++t) {
        const int jt = t * JT;
        const int cur = t & 1, nxt = cur ^ 1;
        // ---- barrier A: own stage(t) done (adj(t) stays in flight), rendezvous
        asm volatile("s_waitcnt vmcnt(8)" ::: "memory");
        SFENCE();
        __builtin_amdgcn_s_barrier();
        SFENCE();
        // ---- issue stage(t+1) into sh[nxt] (reads ended at barrier B(t-1))
        if (t < NT - 1) {
#pragma unroll
            for (int i = 0; i < 4; ++i)
                glds16(gsrc[i] + jt + JT, &sh[nxt][(wv * 4 + i) * 4][0]);
        }
        SFENCE();
        // ---- issue adj(t+1)
        if (t < NT - 1) {
#pragma unroll
            for (int v = 0; v < 8; ++v)
                adjv[nxt][v] = __builtin_nontemporal_load(
                    (const i32x4*)(apL + (size_t)(2 * v) * N + jt + JT));
        }
        SFENCE();
        // ---- C: exp-weights from adjv[cur] -> wl (wave-private, no barrier)
        const f32x4 fd0 = *(const f32x4*)&sfd[jt + col4];
#pragma unroll
        for (int v = 0; v < 8; ++v) {
            const float fs_l = rpar ? fsr[2 * v + 1] : fsr[2 * v];
            const float sh_l = rpar ? shl[2 * v + 1] : shl[2 * v];
            bf16x4 wb;
#pragma unroll
            for (int c = 0; c < 4; ++c) {
                float e = fs_l + fd0[c];
                e = fmaxf(e, ALPHA * e);
                const float ex = __builtin_amdgcn_exp2f(e * LOG2E - sh_l);
                wb[c] = (__bf16)(adjv[cur][v][c] > 0 ? ex : 0.f);
            }
            const int rr = 2 * v + rpar;
            *(bf16x4*)&wl[wv][rr][col4 ^ ((rr & 7) << 3)] = wb;
        }
        SFENCE();
        // ---- D: MFMA; A from wl, B from sh[cur] (swizzled read)
#pragma unroll
        for (int jj0 = 0; jj0 < JT; jj0 += 64) {
#pragma unroll
            for (int u = 0; u < 2; ++u) {
                const int cb = jj0 + u * 32 + quad * 8;
                const int cs = cb ^ ((m & 7) << 3);
                const bf16x8 af = *(const bf16x8*)&wl[wv][m][cs];
#pragma unroll
                for (int tt = 0; tt < 4; ++tt) {
                    const bf16x8 bfr = *(const bf16x8*)&sh[cur][tt * 16 + m][cs];
                    acc[tt] = __builtin_amdgcn_mfma_f32_16x16x32_bf16(af, bfr, acc[tt], 0, 0, 0);
                }
                accl = __builtin_amdgcn_mfma_f32_16x16x32_bf16(af, bones, accl, 0, 0, 0);
            }
        }
        SFENCE();
        // ---- barrier B: all waves done reading sh[cur]
        if (t < NT - 1) {
            asm volatile("s_waitcnt lgkmcnt(0)" ::: "memory");
            SFENCE();
            __builtin_amdgcn_s_barrier();
            SFENCE();
        }
    }
    // epilogue: plain stores to this y-slice's partial buffers
    float* npb = num_part + (size_t)blockIdx.y * N * FOUT;
#pragma unroll
    for (int t = 0; t < 4; ++t)
#pragma unroll
        for (int r = 0; r < 4; ++r)
            npb[(size_t)(i0 + quad * 4 + r) * FOUT + t * 16 + m] = acc[t][r];
    if (m == 0) {
#pragma unroll
        for (int r = 0; r < 4; ++r)
            lsum_part[(size_t)blockIdx.y * N + i0 + quad * 4 + r] = accl[r];
    }
}

// ---------- k4: out = leaky(sum_p num_part / sum_p lsum_part, 0.01) --------
__global__ __launch_bounds__(256) void k4_norm(float* __restrict__ out,
                                               const float* __restrict__ num_part,
                                               const float* __restrict__ lsum_part) {
    const int idx = blockIdx.x * 256 + threadIdx.x;
    const int i = idx >> 6;
    float s = 0.f, l = 0.f;
#pragma unroll
    for (int p = 0; p < 4; ++p) {
        s += num_part[(size_t)p * N * FOUT + idx];
        l += lsum_part[(size_t)p * N + i];
    }
    const float v = s / (l > 0.f ? l : 1.f);
    out[idx] = v > 0.f ? v : 0.01f * v;
}

extern "C" void kernel_launch(void* const* d_in, const int* in_sizes, int n_in,
                              void* d_out, int out_size, void* d_ws, size_t ws_size,
                              hipStream_t stream) {
    const float* in = (const float*)d_in[0];
    const int* adj = (const int*)d_in[1];
    const float* W = (const float*)d_in[2];
    const float* a = (const float*)d_in[3];
    float* out = (float*)d_out;

    char* ws = (char*)d_ws;
    unsigned* Mkey = (unsigned*)ws;
    float* f_src = (float*)(ws + 32832);
    float* f_dst = (float*)(ws + 65600);
    __bf16* WtG = (__bf16*)(ws + 98368);
    __bf16* hT = (__bf16*)(ws + 163904);
    float* num_part = (float*)(ws + 1212480);
    float* lsum_part = (float*)(ws + 17989696);

    k_wt<<<64, 64, 0, stream>>>(W, WtG, Mkey);  // also zero-inits Mkey
    k12<<<N / 16, 256, 0, stream>>>(in, WtG, a, f_src, f_dst, Mkey, hT);

    dim3 g3(N / 64, 4);
    k3_attn<<<g3, 256, 0, stream>>>(adj, f_src, f_dst, Mkey, hT, num_part, lsum_part);
    k4_norm<<<(N * FOUT) / 256, 256, 0, stream>>>(out, num_part, lsum_part);
}